// Round 4
// baseline (771.887 us; speedup 1.0000x reference)
//
#include <hip/hip_runtime.h>
#include <hip/hip_bf16.h>

// GCN forward on MI355X.
//   adjb = bf16(adj)  [10048][10048], K-pad cols zeroed   (cvt_adj, ~600 MB stream)
//   S1t  = (feat @ W1)^T   bf16 [HID][KP]
//   x1   = relu(adj @ S1 + b1)  split-K=4 partials -> relu_bias_fin -> d_out + x1b
//   S2t  = (x1 @ W2)^T     bf16 [CLS][KP]
//   x2   = adj @ S2 + b2   split-K=8 partials -> logsoftmax_fin -> d_out+N*HID
//
// R4: all-bf16 GEMM operands (adj pre-converted once), padded K (=10048) and
// padded row allocations so staging has ZERO guards, unpadded m97-style LDS
// (16B-aligned b128 ops), depth-2 register prefetch (2 tiles in flight/wave).

#define NROW 10000
#define FIN  512
#define HID  256
#define NCLS 64
#define KP   10048          // NROW rounded up to 64
#define KSPLIT2 4
#define KSPAN2  2560        // splits: 40,40,40,37 iters
#define KSPLIT4 8
#define KSPAN4  1280        // splits: 20x7,17 iters

typedef __bf16 bf8_t __attribute__((ext_vector_type(8)));
typedef __bf16 bf4_t __attribute__((ext_vector_type(4)));
typedef float  f4_t  __attribute__((ext_vector_type(4)));
typedef short  s8_t  __attribute__((ext_vector_type(8)));

// ---------------- adj fp32 -> bf16 with zeroed K-pad cols ----------------
// grid (10, NROW), 256 thr: lane handles 4 consecutive cols (f4 load, bf4 store).
__global__ void cvt_adj(const float* __restrict__ in, __bf16* __restrict__ out) {
    int idx = blockIdx.x * 256 + threadIdx.x;          // col group
    if (idx >= KP / 4) return;
    int r = blockIdx.y;
    int c0 = idx * 4;
    bf4_t o;
    if (c0 + 4 <= NROW) {
        f4_t v = *(const f4_t*)(in + (long)r * NROW + c0);
        o[0] = (__bf16)v[0]; o[1] = (__bf16)v[1]; o[2] = (__bf16)v[2]; o[3] = (__bf16)v[3];
    } else {
        o[0] = (__bf16)0.f; o[1] = (__bf16)0.f; o[2] = (__bf16)0.f; o[3] = (__bf16)0.f;
    }
    *(bf4_t*)(out + (long)r * KP + c0) = o;
}

__global__ void cvt_f32_bf16(const float* __restrict__ in, __bf16* __restrict__ out, int n) {
    int stride = gridDim.x * blockDim.x * 4;
    for (int i = (blockIdx.x * blockDim.x + threadIdx.x) * 4; i < n; i += stride) {
        f4_t v = *(const f4_t*)(in + i);
        bf4_t o;
        o[0] = (__bf16)v[0]; o[1] = (__bf16)v[1]; o[2] = (__bf16)v[2]; o[3] = (__bf16)v[3];
        *(bf4_t*)(out + i) = o;
    }
}

// in [K][Nn] fp32 row-major -> out [Nn][K] bf16 (weights only; tiny)
__global__ void cvt_transpose(const float* __restrict__ in, __bf16* __restrict__ out, int K, int Nn) {
    int idx = blockIdx.x * 256 + threadIdx.x;
    if (idx < K * Nn) {
        int k = idx / Nn, n = idx % Nn;
        out[n * K + k] = (__bf16)in[idx];
    }
}

// ---------------- GEMM: D[M][Nn] = A[M][K] * Bt[Nn][K]^T, all bf16 ----------------
// No staging guards: callers guarantee row-padded allocations and zeroed K-pad.
// EPI 0: store bf16 row-major to outB (ldo)
// EPI 2: fp32 partial -> outF + blockIdx.z*partStride
template<int BM, int BN, int BK, int EPI>
__global__ void __launch_bounds__(256, 3)
gemm_bt(const __bf16* __restrict__ A, const __bf16* __restrict__ Bt,
        int M, int Nn, int K, int lda, int ldb, int kspan,
        float* __restrict__ outF, __bf16* __restrict__ outB,
        int ldo, long partStride)
{
    constexpr int WM = BM / 2, WN = BN / 2;      // 2x2 waves per block
    constexpr int MI = WM / 16, NI = WN / 16;
    constexpr int CPR = BK / 8;                  // 16B chunks per row
    constexpr int ACH = BM * BK / 8 / 256;       // 16B chunks per thread (A)
    constexpr int BCH = BN * BK / 8 / 256;
    __shared__ __bf16 As[BM * BK];               // unpadded: 128B rows, 16B aligned
    __shared__ __bf16 Bs[BN * BK];

    const int tid  = threadIdx.x;
    const int lane = tid & 63;
    const int wave = tid >> 6;
    const int wm = wave >> 1, wn = wave & 1;
    const int m0 = blockIdx.x * BM;
    const int n0 = blockIdx.y * BN;
    const int kbase = blockIdx.z * kspan;
    const int kend  = min(K, kbase + kspan);     // multiple of BK by construction

    f4_t acc[MI][NI];
    #pragma unroll
    for (int i = 0; i < MI; i++)
        #pragma unroll
        for (int j = 0; j < NI; j++)
            acc[i][j] = f4_t{0.f, 0.f, 0.f, 0.f};

    const int lrow  = lane & 15;
    const int koff0 = (lane >> 4) * 8;

    s8_t pA0[ACH], pB0[BCH], pA1[ACH], pB1[BCH];

    auto issueTile = [&](int k0, s8_t* pa, s8_t* pb) {
        #pragma unroll
        for (int i = 0; i < ACH; ++i) {
            int idx = tid + i * 256;
            pa[i] = *(const s8_t*)(A + (long)(m0 + idx / CPR) * lda + k0 + (idx % CPR) * 8);
        }
        #pragma unroll
        for (int i = 0; i < BCH; ++i) {
            int idx = tid + i * 256;
            pb[i] = *(const s8_t*)(Bt + (long)(n0 + idx / CPR) * ldb + k0 + (idx % CPR) * 8);
        }
    };
    auto storeTile = [&](s8_t* pa, s8_t* pb) {
        #pragma unroll
        for (int i = 0; i < ACH; ++i) *(s8_t*)&As[(tid + i * 256) * 8] = pa[i];
        #pragma unroll
        for (int i = 0; i < BCH; ++i) *(s8_t*)&Bs[(tid + i * 256) * 8] = pb[i];
    };

    // depth-2 pipeline: tiles k+1 and k+2 in flight during compute of tile k
    issueTile(kbase, pA0, pB0);
    issueTile(kbase + BK, pA1, pB1);             // all kernels have >=4 k-iters
    int it = 0;
    for (int k0 = kbase; k0 < kend; k0 += BK, ++it) {
        if ((it & 1) == 0) storeTile(pA0, pB0); else storeTile(pA1, pB1);
        __syncthreads();
        int kpre = k0 + 2 * BK;
        if (kpre < kend) {
            if ((it & 1) == 0) issueTile(kpre, pA0, pB0); else issueTile(kpre, pA1, pB1);
        }
        #pragma unroll
        for (int ks = 0; ks < BK; ks += 32) {
            bf8_t af[MI], bfv[NI];
            #pragma unroll
            for (int mi = 0; mi < MI; mi++)
                af[mi] = *(const bf8_t*)&As[(wm * WM + mi * 16 + lrow) * BK + ks + koff0];
            #pragma unroll
            for (int ni = 0; ni < NI; ni++)
                bfv[ni] = *(const bf8_t*)&Bs[(wn * WN + ni * 16 + lrow) * BK + ks + koff0];
            #pragma unroll
            for (int mi = 0; mi < MI; mi++)
                #pragma unroll
                for (int ni = 0; ni < NI; ni++)
                    acc[mi][ni] = __builtin_amdgcn_mfma_f32_16x16x32_bf16(
                        af[mi], bfv[ni], acc[mi][ni], 0, 0, 0);
        }
        __syncthreads();
    }

    // ---- epilogue ----  C/D layout: col = lane&15, row = (lane>>4)*4 + reg
    const int erow = wm * WM + (lane >> 4) * 4;
    const int ecol = wn * WN + lrow;
    #pragma unroll
    for (int mi = 0; mi < MI; mi++) {
        #pragma unroll
        for (int ni = 0; ni < NI; ni++) {
            #pragma unroll
            for (int r = 0; r < 4; r++) {
                int grow = m0 + erow + mi * 16 + r;
                int gcol = n0 + ecol + ni * 16;
                if (grow < M && gcol < Nn) {
                    float v = acc[mi][ni][r];
                    if constexpr (EPI == 0) {
                        outB[(long)grow * ldo + gcol] = (__bf16)v;
                    } else {
                        outF[blockIdx.z * partStride + (long)grow * ldo + gcol] = v;
                    }
                }
            }
        }
    }
}

// ---------------- GEMM2 reduce: x1 = relu(sum(part) + b1) ----------------
__global__ void relu_bias_fin(const float* __restrict__ part, const float* __restrict__ b1,
                              float* __restrict__ outF, __bf16* __restrict__ outB) {
    long i = (long)(blockIdx.x * 256 + threadIdx.x) * 4;
    f4_t v = *(const f4_t*)(part + i);
    #pragma unroll
    for (int s = 1; s < KSPLIT2; s++) {
        f4_t p = *(const f4_t*)(part + (long)s * NROW * HID + i);
        v[0] += p[0]; v[1] += p[1]; v[2] += p[2]; v[3] += p[3];
    }
    int col = (int)(i & (HID - 1));
    f4_t b = *(const f4_t*)(b1 + col);
    f4_t y;
    bf4_t yb;
    #pragma unroll
    for (int j = 0; j < 4; j++) {
        y[j] = fmaxf(v[j] + b[j], 0.f);
        yb[j] = (__bf16)y[j];
    }
    *(f4_t*)(outF + i) = y;
    *(bf4_t*)(outB + i) = yb;    // x1b row-major [NROW][HID], pad rows untouched
}

// ---------------- split-K reduce + bias + log_softmax ----------------
__global__ void logsoftmax_fin(const float* __restrict__ part, const float* __restrict__ b2,
                               float* __restrict__ out, int M) {
    int row  = blockIdx.x * 4 + (threadIdx.x >> 6);
    int lane = threadIdx.x & 63;
    if (row >= M) return;
    float v = b2[lane];
    #pragma unroll
    for (int s = 0; s < KSPLIT4; s++) v += part[((long)s * M + row) * NCLS + lane];
    float m = v;
    #pragma unroll
    for (int off = 32; off > 0; off >>= 1) m = fmaxf(m, __shfl_xor(m, off));
    float e = __expf(v - m);
    float sum = e;
    #pragma unroll
    for (int off = 32; off > 0; off >>= 1) sum += __shfl_xor(sum, off);
    out[(long)row * NCLS + lane] = (v - m) - __logf(sum);
}

extern "C" void kernel_launch(void* const* d_in, const int* in_sizes, int n_in,
                              void* d_out, int out_size, void* d_ws, size_t ws_size,
                              hipStream_t stream) {
    const float* feat = (const float*)d_in[0];
    const float* adj  = (const float*)d_in[1];
    const float* W1   = (const float*)d_in[2];
    const float* b1   = (const float*)d_in[3];
    const float* W2   = (const float*)d_in[4];
    const float* b2   = (const float*)d_in[5];
    float* out = (float*)d_out;
    char* ws = (char*)d_ws;

    // workspace layout (256B aligned) -- ~265 MB total (ws is ~1.6 GB per fill evidence)
    __bf16* adjb  = (__bf16*)(ws);                    // [10048][KP]  201,922,048
    __bf16* featb = (__bf16*)(ws + 201922048);        // [10048][FIN]  10,289,152
    __bf16* W1t   = (__bf16*)(ws + 212211200);        // [HID][FIN]       262,144
    __bf16* W2t   = (__bf16*)(ws + 212473344);        // [CLS][HID]        32,768
    __bf16* S1t   = (__bf16*)(ws + 212506112);        // [HID][KP]      5,144,576
    __bf16* x1b   = (__bf16*)(ws + 217650688);        // [10048][HID]   5,144,576
    __bf16* S2t   = (__bf16*)(ws + 222795264);        // [CLS][KP]      1,286,144
    float*  part  = (float*) (ws + 224081408);        // [4][N][HID]   40,960,000

    // K-pad cols of S1t/S2t must be zero (adjb pad cols zeroed by cvt_adj).
    hipMemsetAsync(S1t, 0, (size_t)HID * KP * 2, stream);
    hipMemsetAsync(S2t, 0, (size_t)NCLS * KP * 2, stream);

    cvt_adj<<<dim3(10, NROW), 256, 0, stream>>>(adj, adjb);
    cvt_f32_bf16<<<640, 256, 0, stream>>>(feat, featb, NROW * FIN);
    cvt_transpose<<<(FIN * HID + 255) / 256, 256, 0, stream>>>(W1, W1t, FIN, HID);
    cvt_transpose<<<(HID * NCLS + 255) / 256, 256, 0, stream>>>(W2, W2t, HID, NCLS);

    // S1t[HID][n] = W1t @ featb^T   (M=256, Nn=NROW, K=FIN)
    gemm_bt<64, 64, 64, 0><<<dim3(4, 157, 1), 256, 0, stream>>>(
        W1t, featb, HID, NROW, FIN, FIN, FIN, FIN,
        nullptr, S1t, KP, 0);

    // x1 partials = adj @ S1   (M=NROW, Nn=HID, K=KP, split-K=4)
    gemm_bt<64, 128, 64, 2><<<dim3(157, 2, KSPLIT2), 256, 0, stream>>>(
        adjb, S1t, NROW, HID, KP, KP, KP, KSPAN2,
        part, nullptr, HID, (long)NROW * HID);

    // x1 = relu(sum + b1) -> out fp32, x1b bf16
    relu_bias_fin<<<NROW * HID / 4 / 256, 256, 0, stream>>>(part, b1, out, x1b);

    // S2t[CLS][n] = W2t @ x1b^T  (M=64, Nn=NROW, K=HID)
    gemm_bt<64, 64, 64, 0><<<dim3(1, 157, 1), 256, 0, stream>>>(
        W2t, x1b, NCLS, NROW, HID, HID, HID, HID,
        nullptr, S2t, KP, 0);

    // x2 partials = adj @ S2   (M=NROW, Nn=NCLS, K=KP, split-K=8)
    gemm_bt<64, 64, 64, 2><<<dim3(157, 1, KSPLIT4), 256, 0, stream>>>(
        adjb, S2t, NROW, NCLS, KP, KP, KP, KSPAN4,
        part, nullptr, NCLS, (long)NROW * NCLS);

    // reduce + b2 + log_softmax -> second output
    logsoftmax_fin<<<2500, 256, 0, stream>>>(part, b2, out + (long)NROW * HID, NROW);
}

// Round 5
// 729.992 us; speedup vs baseline: 1.0574x; 1.0574x over previous
//
#include <hip/hip_runtime.h>
#include <hip/hip_bf16.h>

// GCN forward on MI355X.
//   S1t  = (feat @ W1)^T   bf16 [HID][KP]        (gemm: A=W1t bf16-DMA, B=featb)
//   x1   = relu(adj @ S1 + b1)  split-K=4 fp32 partials -> relu_bias_fin -> d_out + x1b
//   S2t  = (x1 @ W2)^T     bf16 [CLS][KP]
//   x2   = adj @ S2        split-K=8 partials -> logsoftmax_fin -> d_out+N*HID
//
// R5: m97-style K-loop. B tiles staged via async global_load_lds (16B), A (adj
// fp32) staged via f4 register load + cvt + ds_write_b64 (clamped addresses,
// no guards; B pad-K cols zeroed so clamped garbage contributes 0). Single
// LDS buffer, 2 barriers/iter, NO register prefetch (R4's depth-2 prefetch
// was defeated by the vmcnt(0) drain at __syncthreads and blew VGPRs).
// adj read as fp32 directly in both GEMMs: 800 MB total vs 1000 MB with a
// separate cvt pass.

#define NROW 10000
#define FIN  512
#define HID  256
#define NCLS 64
#define KP   10048          // NROW rounded up to 64
#define KSPLIT2 4
#define KSPAN2  2560
#define KSPLIT4 8
#define KSPAN4  1280

typedef __bf16 bf8_t __attribute__((ext_vector_type(8)));
typedef __bf16 bf4_t __attribute__((ext_vector_type(4)));
typedef float  f4_t  __attribute__((ext_vector_type(4)));

typedef __attribute__((address_space(3))) void       lds_void;
typedef const __attribute__((address_space(1))) void glb_void;

__device__ __forceinline__ void dma16(const void* g, void* l) {
    __builtin_amdgcn_global_load_lds((glb_void*)g, (lds_void*)l, 16, 0, 0);
}

// ---------------- converts ----------------
__global__ void cvt_f32_bf16(const float* __restrict__ in, __bf16* __restrict__ out, int n) {
    int stride = gridDim.x * blockDim.x * 4;
    for (int i = (blockIdx.x * blockDim.x + threadIdx.x) * 4; i < n; i += stride) {
        f4_t v = *(const f4_t*)(in + i);
        bf4_t o;
        o[0] = (__bf16)v[0]; o[1] = (__bf16)v[1]; o[2] = (__bf16)v[2]; o[3] = (__bf16)v[3];
        *(bf4_t*)(out + i) = o;
    }
}

// in [K][Nn] fp32 row-major -> out [Nn][K] bf16 (weights only; tiny)
__global__ void cvt_transpose(const float* __restrict__ in, __bf16* __restrict__ out, int K, int Nn) {
    int idx = blockIdx.x * 256 + threadIdx.x;
    if (idx < K * Nn) {
        int k = idx / Nn, n = idx % Nn;
        out[n * K + k] = (__bf16)in[idx];
    }
}

// ---------------- GEMM: D[M][Nn] = A[M][K] * Bt[Nn][K]^T ----------------
// BM = 64 fixed. A: fp32 (AF32=true, cvt during staging, addresses clamped to
// M-1 / Kclamp-4 — requires B pad-K cols zeroed) or bf16 (DMA, M%64==0 rows
// required). Bt rows must be allocated up to gridDim.y*BN (padded), K-extent KP.
// EPI 0: store bf16 row-major to outB (ldo); EPI 2: fp32 partial per z-slice.
template<int BN, bool AF32, int EPI>
__global__ void __launch_bounds__(256, 4)
gemm_bt(const void* __restrict__ Ap, const __bf16* __restrict__ Bt,
        int M, int Nn, int K, int Kclamp, int lda, int ldb, int kspan,
        float* __restrict__ outF, __bf16* __restrict__ outB,
        int ldo, long partStride)
{
    constexpr int BM = 64, BK = 64;
    constexpr int WM = BM / 2, WN = BN / 2;      // 2x2 waves
    constexpr int MI = WM / 16, NI = WN / 16;
    constexpr int BCALLS = BN / 32;              // 1KB DMA chunks per wave (B)
    constexpr int ACALLS = BM / 32;              // (bf16-A path)
    __shared__ __bf16 As[BM * BK];
    __shared__ __bf16 Bs[BN * BK];

    const int tid  = threadIdx.x;
    const int lane = tid & 63;
    const int wave = tid >> 6;
    const int wm = wave >> 1, wn = wave & 1;
    const int m0 = blockIdx.x * BM;
    const int n0 = blockIdx.y * BN;
    const int kbase = blockIdx.z * kspan;
    const int kend  = min(K, kbase + kspan);     // multiple of BK

    f4_t acc[MI][NI];
    #pragma unroll
    for (int i = 0; i < MI; i++)
        #pragma unroll
        for (int j = 0; j < NI; j++)
            acc[i][j] = f4_t{0.f, 0.f, 0.f, 0.f};

    const int lrow  = lane & 15;
    const int koff0 = (lane >> 4) * 8;

    // ---- hoisted staging pointers ----
    // B: DMA chunk c = wave + j*4 covers rows [c*8, c*8+8), 128B per row.
    const __bf16* Brow[BCALLS];
    #pragma unroll
    for (int j = 0; j < BCALLS; ++j) {
        int c = wave + j * 4;
        Brow[j] = Bt + (long)(n0 + c * 8 + (lane >> 3)) * ldb + (lane & 7) * 8;
    }
    // A fp32: 4 chunks/thread, row & col clamped (harmless: B pad-K is zero).
    const float* Arow[4];
    int Acol[4], AldsOff[4];
    const __bf16* ArowB[ACALLS];
    if constexpr (AF32) {
        #pragma unroll
        for (int i = 0; i < 4; ++i) {
            int idx = tid + i * 256;
            int r = idx >> 4, c4 = idx & 15;
            Arow[i] = (const float*)Ap + (long)min(m0 + r, M - 1) * lda;
            Acol[i] = c4 * 4;
            AldsOff[i] = r * BK + c4 * 4;
        }
    } else {
        #pragma unroll
        for (int j = 0; j < ACALLS; ++j) {
            int c = wave + j * 4;
            ArowB[j] = (const __bf16*)Ap + (long)(m0 + c * 8 + (lane >> 3)) * lda + (lane & 7) * 8;
        }
    }

    for (int k0 = kbase; k0 < kend; k0 += BK) {
        // ---- stage A ----
        if constexpr (AF32) {
            f4_t av[4];
            #pragma unroll
            for (int i = 0; i < 4; ++i)
                av[i] = *(const f4_t*)(Arow[i] + min(k0 + Acol[i], Kclamp - 4));
            #pragma unroll
            for (int i = 0; i < 4; ++i) {
                bf4_t o;
                o[0] = (__bf16)av[i][0]; o[1] = (__bf16)av[i][1];
                o[2] = (__bf16)av[i][2]; o[3] = (__bf16)av[i][3];
                *(bf4_t*)&As[AldsOff[i]] = o;
            }
        } else {
            #pragma unroll
            for (int j = 0; j < ACALLS; ++j)
                dma16(ArowB[j] + k0, &As[(wave + j * 4) * 512]);
        }
        // ---- stage B (async DMA) ----
        #pragma unroll
        for (int j = 0; j < BCALLS; ++j)
            dma16(Brow[j] + k0, &Bs[(wave + j * 4) * 512]);

        __syncthreads();   // compiler emits vmcnt(0): DMA + A writes complete

        #pragma unroll
        for (int ks = 0; ks < BK; ks += 32) {
            bf8_t af[MI], bfv[NI];
            #pragma unroll
            for (int mi = 0; mi < MI; mi++)
                af[mi] = *(const bf8_t*)&As[(wm * WM + mi * 16 + lrow) * BK + ks + koff0];
            #pragma unroll
            for (int ni = 0; ni < NI; ni++)
                bfv[ni] = *(const bf8_t*)&Bs[(wn * WN + ni * 16 + lrow) * BK + ks + koff0];
            #pragma unroll
            for (int mi = 0; mi < MI; mi++)
                #pragma unroll
                for (int ni = 0; ni < NI; ni++)
                    acc[mi][ni] = __builtin_amdgcn_mfma_f32_16x16x32_bf16(
                        af[mi], bfv[ni], acc[mi][ni], 0, 0, 0);
        }
        __syncthreads();
    }

    // ---- epilogue ----  C/D layout: col = lane&15, row = (lane>>4)*4 + reg
    const int erow = wm * WM + (lane >> 4) * 4;
    const int ecol = wn * WN + lrow;
    #pragma unroll
    for (int mi = 0; mi < MI; mi++) {
        #pragma unroll
        for (int ni = 0; ni < NI; ni++) {
            #pragma unroll
            for (int r = 0; r < 4; r++) {
                int grow = m0 + erow + mi * 16 + r;
                int gcol = n0 + ecol + ni * 16;
                if (grow < M && gcol < Nn) {
                    float v = acc[mi][ni][r];
                    if constexpr (EPI == 0) {
                        outB[(long)grow * ldo + gcol] = (__bf16)v;
                    } else {
                        outF[blockIdx.z * partStride + (long)grow * ldo + gcol] = v;
                    }
                }
            }
        }
    }
}

// ---------------- GEMM2 reduce: x1 = relu(sum(part) + b1) ----------------
__global__ void relu_bias_fin(const float* __restrict__ part, const float* __restrict__ b1,
                              float* __restrict__ outF, __bf16* __restrict__ outB) {
    long i = (long)(blockIdx.x * 256 + threadIdx.x) * 4;
    f4_t v = *(const f4_t*)(part + i);
    #pragma unroll
    for (int s = 1; s < KSPLIT2; s++) {
        f4_t p = *(const f4_t*)(part + (long)s * NROW * HID + i);
        v[0] += p[0]; v[1] += p[1]; v[2] += p[2]; v[3] += p[3];
    }
    int col = (int)(i & (HID - 1));
    f4_t b = *(const f4_t*)(b1 + col);
    f4_t y;
    bf4_t yb;
    #pragma unroll
    for (int j = 0; j < 4; j++) {
        y[j] = fmaxf(v[j] + b[j], 0.f);
        yb[j] = (__bf16)y[j];
    }
    *(f4_t*)(outF + i) = y;
    *(bf4_t*)(outB + i) = yb;
}

// ---------------- split-K reduce + bias + log_softmax ----------------
__global__ void logsoftmax_fin(const float* __restrict__ part, const float* __restrict__ b2,
                               float* __restrict__ out, int M) {
    int row  = blockIdx.x * 4 + (threadIdx.x >> 6);
    int lane = threadIdx.x & 63;
    if (row >= M) return;
    float v = b2[lane];
    #pragma unroll
    for (int s = 0; s < KSPLIT4; s++) v += part[((long)s * M + row) * NCLS + lane];
    float m = v;
    #pragma unroll
    for (int off = 32; off > 0; off >>= 1) m = fmaxf(m, __shfl_xor(m, off));
    float e = __expf(v - m);
    float sum = e;
    #pragma unroll
    for (int off = 32; off > 0; off >>= 1) sum += __shfl_xor(sum, off);
    out[(long)row * NCLS + lane] = (v - m) - __logf(sum);
}

extern "C" void kernel_launch(void* const* d_in, const int* in_sizes, int n_in,
                              void* d_out, int out_size, void* d_ws, size_t ws_size,
                              hipStream_t stream) {
    const float* feat = (const float*)d_in[0];
    const float* adj  = (const float*)d_in[1];
    const float* W1   = (const float*)d_in[2];
    const float* b1   = (const float*)d_in[3];
    const float* W2   = (const float*)d_in[4];
    const float* b2   = (const float*)d_in[5];
    float* out = (float*)d_out;
    char* ws = (char*)d_ws;

    // workspace layout (256B aligned) -- ~63 MB
    __bf16* featb = (__bf16*)(ws);                    // [10048][FIN]  10,289,152
    __bf16* W1t   = (__bf16*)(ws + 10289152);         // [HID][FIN]       262,144
    __bf16* W2t   = (__bf16*)(ws + 10551296);         // [CLS][HID]        32,768
    __bf16* S1t   = (__bf16*)(ws + 10584064);         // [HID][KP]      5,144,576
    __bf16* x1b   = (__bf16*)(ws + 15728640);         // [10048][HID]   5,144,576
    __bf16* S2t   = (__bf16*)(ws + 20873216);         // [CLS][KP]      1,286,144
    float*  part  = (float*) (ws + 22159360);         // [4][N][HID] / [8][N][CLS]

    // Pad-K cols of S1t/S2t must be zero (A-side clamped loads rely on it).
    hipMemsetAsync(S1t, 0, (size_t)HID * KP * 2, stream);
    hipMemsetAsync(S2t, 0, (size_t)NCLS * KP * 2, stream);

    cvt_f32_bf16<<<640, 256, 0, stream>>>(feat, featb, NROW * FIN);
    cvt_transpose<<<(FIN * HID + 255) / 256, 256, 0, stream>>>(W1, W1t, FIN, HID);
    cvt_transpose<<<(HID * NCLS + 255) / 256, 256, 0, stream>>>(W2, W2t, HID, NCLS);

    // S1t[HID][n] = W1t @ featb^T   (M=256, Nn=NROW, K=FIN)
    gemm_bt<64, false, 0><<<dim3(4, 157, 1), 256, 0, stream>>>(
        W1t, featb, HID, NROW, FIN, FIN, FIN, FIN, FIN,
        nullptr, S1t, KP, 0);

    // x1 partials = adj @ S1   (M=NROW, Nn=HID, K=KP, split-K=4)
    gemm_bt<128, true, 2><<<dim3(157, 2, KSPLIT2), 256, 0, stream>>>(
        adj, S1t, NROW, HID, KP, NROW, NROW, KP, KSPAN2,
        part, nullptr, HID, (long)NROW * HID);

    // x1 = relu(sum + b1) -> out fp32, x1b bf16
    relu_bias_fin<<<NROW * HID / 4 / 256, 256, 0, stream>>>(part, b1, out, x1b);

    // S2t[CLS][n] = W2t @ x1b^T  (M=64, Nn=NROW, K=HID)
    gemm_bt<64, false, 0><<<dim3(1, 157, 1), 256, 0, stream>>>(
        W2t, x1b, NCLS, NROW, HID, HID, HID, HID, HID,
        nullptr, S2t, KP, 0);

    // x2 partials = adj @ S2   (M=NROW, Nn=NCLS, K=KP, split-K=8)
    gemm_bt<64, true, 2><<<dim3(157, 1, KSPLIT4), 256, 0, stream>>>(
        adj, S2t, NROW, NCLS, KP, NROW, NROW, KP, KSPAN4,
        part, nullptr, NCLS, (long)NROW * NCLS);

    // reduce + b2 + log_softmax -> second output
    logsoftmax_fin<<<2500, 256, 0, stream>>>(part, b2, out + (long)NROW * HID, NROW);
}